// Round 2
// baseline (336.665 us; speedup 1.0000x reference)
//
#include <hip/hip_runtime.h>
#include <stdint.h>

#define Bq 4096
#define Tq 200
#define TP 208      // padded to 13 tiles of 16
#define NMT 13
#define Vq 100000

typedef __attribute__((ext_vector_type(8))) short short8;   // 8 bf16 in 4 VGPRs
typedef __attribute__((ext_vector_type(4))) float f32x4;

static __device__ __forceinline__ unsigned short f2b(float f) {
    unsigned int u = __builtin_bit_cast(unsigned int, f);
    u = u + 0x7fffu + ((u >> 16) & 1u);            // RNE
    return (unsigned short)(u >> 16);
}
static __device__ __forceinline__ float b2f(unsigned short s) {
    unsigned int u = ((unsigned int)s) << 16;
    return __builtin_bit_cast(float, u);
}
static __device__ __forceinline__ short8 ld8(const unsigned short* p) {
    return *(const short8*)p;
}

// ---------------- K0: table2[v][j] = embed[v] @ (W0 + W2), stored bf16 ----------------
extern "C" __global__ __launch_bounds__(256) void k_table2(
    const float* __restrict__ embed, const float* __restrict__ aw1,
    unsigned short* __restrict__ t2tab)
{
    __shared__ alignas(16) float s_W[64][64];
    __shared__ alignas(16) float s_e[64][64];
    int tid = threadIdx.x;
    int v0 = blockIdx.x * 64;
    for (int idx = tid; idx < 4096; idx += 256) {
        int i = idx >> 6, j = idx & 63;
        s_W[i][j] = aw1[i*64 + j] + aw1[(128 + i)*64 + j];
        int v = v0 + i;
        s_e[i][j] = (v < Vq) ? embed[(long)v*64 + j] : 0.f;
    }
    __syncthreads();
    int j = tid & 63, rq = tid >> 6;
    float acc[16];
    #pragma unroll
    for (int r = 0; r < 16; ++r) acc[r] = 0.f;
    for (int i0 = 0; i0 < 64; i0 += 4) {
        float w0 = s_W[i0+0][j], w1 = s_W[i0+1][j], w2 = s_W[i0+2][j], w3 = s_W[i0+3][j];
        #pragma unroll
        for (int r = 0; r < 16; ++r) {
            f32x4 e = *(const f32x4*)&s_e[rq*16 + r][i0];
            acc[r] += e.x*w0 + e.y*w1 + e.z*w2 + e.w*w3;
        }
    }
    #pragma unroll
    for (int r = 0; r < 16; ++r) {
        int v = v0 + rq*16 + r;
        if (v < Vq) t2tab[(long)v*64 + j] = f2b(acc[r]);
    }
}

// ---------------- KA: per-b fused attention -> mlp_in[b][128] ----------------
extern "C" __global__ __launch_bounds__(256) void k_attn(
    const int* __restrict__ target, const int* __restrict__ hist,
    const int* __restrict__ mask,
    const float* __restrict__ embed, const float* __restrict__ aw1,
    const float* __restrict__ ab1, const float* __restrict__ aw2,
    const float* __restrict__ ab2, const float* __restrict__ aow,
    const float* __restrict__ aob, const unsigned short* __restrict__ t2tab,
    float* __restrict__ mlpin)
{
    __shared__ int s_id[TP];
    __shared__ float s_q[64];
    __shared__ float s_qc[64];
    __shared__ float s_qcp[4][64];
    __shared__ alignas(16) unsigned short s_hq[TP][64];   // hist*q, bf16
    __shared__ alignas(16) unsigned short s_h1[TP][64];   // layer1 out, bf16
    __shared__ alignas(16) unsigned short s_WpT[64][64];  // W3 transposed: [j][k]
    __shared__ alignas(16) unsigned short s_aw2T[32][64]; // aw2 transposed: [k][j]
    __shared__ float s_sc[TP];
    __shared__ float s_aow[32];
    __shared__ float s_ab2[32];
    __shared__ float s_red[8];
    __shared__ float s_intp[4][64];

    int tid = threadIdx.x;
    int lane = tid & 63;
    int wv = tid >> 6;
    int b = blockIdx.x;

    int tgt = target[b];
    if (tid < 64) s_q[tid] = embed[(long)tgt*64 + tid];
    for (int t = tid; t < TP; t += 256) s_id[t] = hist[b*Tq + ((t < Tq) ? t : 0)];
    if (tid < 32) { s_aow[tid] = aow[tid]; s_ab2[tid] = ab2[tid]; }
    __syncthreads();

    // stage W3^T (bf16) : s_WpT[j][i] = aw1[192+i][j]
    for (int idx = tid; idx < 4096; idx += 256) {
        int i = idx >> 6, jj = idx & 63;
        s_WpT[jj][i] = f2b(aw1[(192 + i)*64 + jj]);
    }
    // stage aw2^T (bf16) : s_aw2T[k][j] = aw2[j][k]
    for (int idx = tid; idx < 2048; idx += 256) {
        int jj = idx >> 5, k = idx & 31;
        s_aw2T[k][jj] = f2b(aw2[jj*32 + k]);
    }
    // qc partials: qc[j] = ab1[j] + sum_i q[i]*(W1-W2)[i][j]
    {
        float acc = 0.f;
        #pragma unroll
        for (int ii = 0; ii < 16; ++ii) {
            int i = wv*16 + ii;
            acc += s_q[i] * (aw1[(64 + i)*64 + lane] - aw1[(128 + i)*64 + lane]);
        }
        s_qcp[wv][lane] = acc;
    }
    // stage hq = hist*q (bf16)
    for (int idx = tid; idx < TP*64; idx += 256) {
        int t = idx >> 6, jj = idx & 63;
        float hv = embed[(long)s_id[t]*64 + jj];
        s_hq[t][jj] = f2b(hv * s_q[jj]);
    }
    __syncthreads();
    if (tid < 64) s_qc[tid] = ab1[tid] + s_qcp[0][tid] + s_qcp[1][tid] + s_qcp[2][tid] + s_qcp[3][tid];
    __syncthreads();

    int r16 = lane & 15;
    int kg  = lane >> 4;
    float aob0 = aob[0];

    // scores: per-wave private M-tiles -> no barriers inside
    for (int m = wv; m < NMT; m += 4) {
        int row0 = m*16;
        short8 a0 = ld8(&s_hq[row0 + r16][kg*8]);
        short8 a1 = ld8(&s_hq[row0 + r16][32 + kg*8]);
        f32x4 d[4];
        #pragma unroll
        for (int n = 0; n < 4; ++n) {
            short8 b0 = ld8(&s_WpT[n*16 + r16][kg*8]);
            short8 b1 = ld8(&s_WpT[n*16 + r16][32 + kg*8]);
            f32x4 z = {0.f, 0.f, 0.f, 0.f};
            z = __builtin_amdgcn_mfma_f32_16x16x32_bf16(a0, b0, z, 0, 0, 0);
            z = __builtin_amdgcn_mfma_f32_16x16x32_bf16(a1, b1, z, 0, 0, 0);
            d[n] = z;
        }
        // h1 = relu(p + qc + table2[id])  (D layout: col=lane&15, row=(lane>>4)*4+r)
        #pragma unroll
        for (int n = 0; n < 4; ++n) {
            int col = n*16 + r16;
            float qc = s_qc[col];
            #pragma unroll
            for (int r = 0; r < 4; ++r) {
                int row = row0 + kg*4 + r;
                float t2 = b2f(t2tab[(long)s_id[row]*64 + col]);
                float v = d[n][r] + qc + t2;
                s_h1[row][col] = f2b(fmaxf(v, 0.f));
            }
        }
        // layer2 (same wave wrote the whole tile -> wave-synchronous LDS reuse)
        short8 ha0 = ld8(&s_h1[row0 + r16][kg*8]);
        short8 ha1 = ld8(&s_h1[row0 + r16][32 + kg*8]);
        f32x4 e[2];
        #pragma unroll
        for (int n = 0; n < 2; ++n) {
            short8 b0 = ld8(&s_aw2T[n*16 + r16][kg*8]);
            short8 b1 = ld8(&s_aw2T[n*16 + r16][32 + kg*8]);
            f32x4 z = {0.f, 0.f, 0.f, 0.f};
            z = __builtin_amdgcn_mfma_f32_16x16x32_bf16(ha0, b0, z, 0, 0, 0);
            z = __builtin_amdgcn_mfma_f32_16x16x32_bf16(ha1, b1, z, 0, 0, 0);
            e[n] = z;
        }
        // layer3: score = relu(h2 + ab2) @ aow  (+aob), reduce across 16 lanes
        #pragma unroll
        for (int r = 0; r < 4; ++r) {
            float h20 = fmaxf(e[0][r] + s_ab2[r16], 0.f);
            float h21 = fmaxf(e[1][r] + s_ab2[16 + r16], 0.f);
            float p = h20 * s_aow[r16] + h21 * s_aow[16 + r16];
            p += __shfl_xor(p, 1);
            p += __shfl_xor(p, 2);
            p += __shfl_xor(p, 4);
            p += __shfl_xor(p, 8);
            if (r16 == 0) s_sc[row0 + kg*4 + r] = p + aob0;
        }
    }
    __syncthreads();

    // softmax over t<200 (masked) — mask is int32 (bool uploaded as int)
    float sc = -1e30f;
    if (tid < Tq) {
        int mk = mask[(long)b*Tq + tid];
        sc = mk ? s_sc[tid] : -1e9f;
    }
    float mx = sc;
    #pragma unroll
    for (int off = 1; off < 64; off <<= 1) mx = fmaxf(mx, __shfl_xor(mx, off));
    if (lane == 0) s_red[wv] = mx;
    __syncthreads();
    mx = fmaxf(fmaxf(s_red[0], s_red[1]), fmaxf(s_red[2], s_red[3]));
    float ex = (tid < Tq) ? expf(sc - mx) : 0.f;
    float sm = ex;
    #pragma unroll
    for (int off = 1; off < 64; off <<= 1) sm += __shfl_xor(sm, off);
    if (lane == 0) s_red[4 + wv] = sm;
    __syncthreads();
    float tot = s_red[4] + s_red[5] + s_red[6] + s_red[7];
    if (tid < Tq) s_sc[tid] = ex / tot;
    __syncthreads();

    // interest[j] = sum_t w_t * hist_emb[t][j]  (re-gather rows, L2/L3-resident)
    float acc = 0.f;
    for (int t = wv; t < Tq; t += 4)
        acc += s_sc[t] * embed[(long)s_id[t]*64 + lane];
    s_intp[wv][lane] = acc;
    __syncthreads();
    if (tid < 64) {
        float inter = s_intp[0][tid] + s_intp[1][tid] + s_intp[2][tid] + s_intp[3][tid];
        mlpin[(long)b*128 + tid] = s_q[tid];
        mlpin[(long)b*128 + 64 + tid] = inter;
    }
}

// ---------------- KB: final MLP 128->256->128->1, fp32 ----------------
extern "C" __global__ __launch_bounds__(256) void k_final(
    const float* __restrict__ mlpin, const float* __restrict__ mw1,
    const float* __restrict__ mb1, const float* __restrict__ mw2,
    const float* __restrict__ mb2, const float* __restrict__ ow,
    const float* __restrict__ ob, float* __restrict__ out)
{
    __shared__ alignas(16) float s_in[16][128];
    __shared__ alignas(16) float s_g1[16][256];
    __shared__ alignas(16) float s_g2[16][128];
    int tid = threadIdx.x;
    long b0 = (long)blockIdx.x * 16;
    for (int idx = tid; idx < 2048; idx += 256) s_in[idx >> 7][idx & 127] = mlpin[b0*128 + idx];
    __syncthreads();
    {
        float acc[16];
        float bias = mb1[tid];
        #pragma unroll
        for (int r = 0; r < 16; ++r) acc[r] = bias;
        for (int i0 = 0; i0 < 128; i0 += 4) {
            float w0 = mw1[(i0+0)*256 + tid];
            float w1 = mw1[(i0+1)*256 + tid];
            float w2 = mw1[(i0+2)*256 + tid];
            float w3 = mw1[(i0+3)*256 + tid];
            #pragma unroll
            for (int r = 0; r < 16; ++r) {
                f32x4 e = *(const f32x4*)&s_in[r][i0];
                acc[r] += e.x*w0 + e.y*w1 + e.z*w2 + e.w*w3;
            }
        }
        #pragma unroll
        for (int r = 0; r < 16; ++r) s_g1[r][tid] = fmaxf(acc[r], 0.f);
    }
    __syncthreads();
    {
        int o = tid & 127, rh = tid >> 7;
        float acc[8];
        float bias = mb2[o];
        #pragma unroll
        for (int r = 0; r < 8; ++r) acc[r] = bias;
        for (int i0 = 0; i0 < 256; i0 += 4) {
            float w0 = mw2[(i0+0)*128 + o];
            float w1 = mw2[(i0+1)*128 + o];
            float w2 = mw2[(i0+2)*128 + o];
            float w3 = mw2[(i0+3)*128 + o];
            #pragma unroll
            for (int r = 0; r < 8; ++r) {
                f32x4 e = *(const f32x4*)&s_g1[rh*8 + r][i0];
                acc[r] += e.x*w0 + e.y*w1 + e.z*w2 + e.w*w3;
            }
        }
        #pragma unroll
        for (int r = 0; r < 8; ++r) s_g2[rh*8 + r][o] = fmaxf(acc[r], 0.f);
    }
    __syncthreads();
    {
        int r = tid >> 4, l16 = tid & 15;
        float acc = 0.f;
        for (int o = l16; o < 128; o += 16) acc += s_g2[r][o] * ow[o];
        acc += __shfl_xor(acc, 1);
        acc += __shfl_xor(acc, 2);
        acc += __shfl_xor(acc, 4);
        acc += __shfl_xor(acc, 8);
        if (l16 == 0) out[b0 + r] = acc + ob[0];
    }
}

extern "C" void kernel_launch(void* const* d_in, const int* in_sizes, int n_in,
                              void* d_out, int out_size, void* d_ws, size_t ws_size,
                              hipStream_t stream)
{
    const int*   target = (const int*)d_in[0];
    const int*   hist   = (const int*)d_in[1];
    const int*   mask   = (const int*)d_in[2];
    const float* embed  = (const float*)d_in[3];
    const float* aw1    = (const float*)d_in[4];
    const float* ab1    = (const float*)d_in[5];
    const float* aw2    = (const float*)d_in[6];
    const float* ab2    = (const float*)d_in[7];
    const float* aow    = (const float*)d_in[8];
    const float* aob    = (const float*)d_in[9];
    const float* mw1    = (const float*)d_in[10];
    const float* mb1    = (const float*)d_in[11];
    const float* mw2    = (const float*)d_in[12];
    const float* mb2    = (const float*)d_in[13];
    const float* ow     = (const float*)d_in[14];
    const float* ob     = (const float*)d_in[15];
    float* out = (float*)d_out;

    unsigned short* t2tab = (unsigned short*)d_ws;                       // 12.8 MB
    float* mlpin = (float*)((char*)d_ws + (size_t)Vq * 64 * 2);          // +2 MB

    k_table2<<<(Vq + 63) / 64, 256, 0, stream>>>(embed, aw1, t2tab);
    k_attn<<<Bq, 256, 0, stream>>>(target, hist, mask, embed, aw1, ab1, aw2,
                                   ab2, aow, aob, t2tab, mlpin);
    k_final<<<Bq / 16, 256, 0, stream>>>(mlpin, mw1, mb1, mw2, mb2, ow, ob, out);
}

// Round 5
// 136.134 us; speedup vs baseline: 2.4730x; 2.4730x over previous
//
#include <hip/hip_runtime.h>
#include <stdint.h>

#define Bq 4096
#define Tq 200
#define TP 208      // padded to 13 tiles of 16
#define NMT 13
#define Vq 100000

typedef __attribute__((ext_vector_type(8))) short short8;   // 8 bf16 in 4 VGPRs
typedef __attribute__((ext_vector_type(4))) float f32x4;
typedef __attribute__((ext_vector_type(4))) unsigned short bfx4;

static __device__ __forceinline__ unsigned short f2b(float f) {
    unsigned int u = __builtin_bit_cast(unsigned int, f);
    u = u + 0x7fffu + ((u >> 16) & 1u);            // RNE
    return (unsigned short)(u >> 16);
}
static __device__ __forceinline__ float b2f(unsigned short s) {
    unsigned int u = ((unsigned int)s) << 16;
    return __builtin_bit_cast(float, u);
}

// swizzled [R][64]-bf16 tile helpers: byte = (row*128 + col*2) ^ ((row&7)<<4)
static __device__ __forceinline__ short8 ld8sw(const unsigned short* base, int row, int col8) {
    return *(const short8*)((const char*)base + (((row << 7) + (col8 << 1)) ^ ((row & 7) << 4)));
}
static __device__ __forceinline__ void st16sw(unsigned short* base, int row, int col, unsigned short v) {
    *(unsigned short*)((char*)base + (((row << 7) + (col << 1)) ^ ((row & 7) << 4))) = v;
}
static __device__ __forceinline__ void st64sw(unsigned short* base, int row, int col4, bfx4 v) {
    *(bfx4*)((char*)base + (((row << 7) + (col4 << 3)) ^ ((row & 7) << 4))) = v;
}
static __device__ __forceinline__ unsigned short ld16sw(const unsigned short* base, int row, int col) {
    return *(const unsigned short*)((const char*)base + (((row << 7) + (col << 1)) ^ ((row & 7) << 4)));
}

// ---------------- KA: per-b fused attention -> mlp_in[b][128] ----------------
extern "C" __global__ __launch_bounds__(256, 3) void k_attn(
    const int* __restrict__ target, const int* __restrict__ hist,
    const int* __restrict__ mask,
    const float* __restrict__ embed, const float* __restrict__ aw1,
    const float* __restrict__ ab1, const float* __restrict__ aw2,
    const float* __restrict__ ab2, const float* __restrict__ aow,
    const float* __restrict__ aob,
    float* __restrict__ mlpin)
{
    __shared__ int s_id[TP];
    __shared__ float s_q[64];
    __shared__ float s_qc[64];
    __shared__ float s_qcp[4][64];
    __shared__ alignas(16) unsigned short s_hist[TP * 64];   // hist emb, bf16, swizzled
    __shared__ alignas(16) unsigned short s_WeffT[64 * 64];  // (W0+W2+diag(q)W3)^T, swizzled
    __shared__ alignas(16) unsigned short s_aw2T[32 * 64];   // aw2^T, swizzled
    __shared__ alignas(16) unsigned short s_h1[4 * 16 * 64]; // per-wave layer1 scratch, swizzled
    __shared__ float s_sc[TP];
    __shared__ float s_aow[32];
    __shared__ float s_ab2[32];
    __shared__ float s_red[8];
    __shared__ float s_intp[4][64];

    int tid = threadIdx.x;
    int lane = tid & 63;
    int wv = tid >> 6;
    int b = blockIdx.x;

    int tgt = target[b];
    if (tid < 64) s_q[tid] = embed[(long)tgt * 64 + tid];
    for (int t = tid; t < TP; t += 256) s_id[t] = hist[b * Tq + ((t < Tq) ? t : 0)];
    if (tid < 32) { s_aow[tid] = aow[tid]; s_ab2[tid] = ab2[tid]; }
    __syncthreads();

    // WeffT[j][i] = W0[i][j] + W2[i][j] + q[i]*W3[i][j]  (coalesced reads, swizzled write)
    for (int idx = tid; idx < 4096; idx += 256) {
        int i = idx >> 6, j = idx & 63;
        float w = aw1[i * 64 + j] + aw1[(128 + i) * 64 + j] + s_q[i] * aw1[(192 + i) * 64 + j];
        st16sw(s_WeffT, j, i, f2b(w));
    }
    // aw2T[k][j] = aw2[j][k]  (tiny, L2-hot)
    for (int idx = tid; idx < 2048; idx += 256) {
        int j = idx >> 5, k = idx & 31;
        st16sw(s_aw2T, k, j, f2b(aw2[j * 32 + k]));
    }
    // qc partials: qc[j] = ab1[j] + sum_i q[i]*(W1-W2)[i][j]
    {
        float acc = 0.f;
        #pragma unroll
        for (int ii = 0; ii < 16; ++ii) {
            int i = wv * 16 + ii;
            acc += s_q[i] * (aw1[(64 + i) * 64 + lane] - aw1[(128 + i) * 64 + lane]);
        }
        s_qcp[wv][lane] = acc;
    }
    // stage hist rows as bf16 (vectorized 16B gathers)
    for (int u = tid; u < TP * 16; u += 256) {
        int t = u >> 4, j4 = u & 15;
        f32x4 e = *(const f32x4*)&embed[(long)s_id[t] * 64 + j4 * 4];
        bfx4 p = { f2b(e.x), f2b(e.y), f2b(e.z), f2b(e.w) };
        st64sw(s_hist, t, j4, p);
    }
    __syncthreads();
    if (tid < 64) s_qc[tid] = ab1[tid] + s_qcp[0][tid] + s_qcp[1][tid] + s_qcp[2][tid] + s_qcp[3][tid];
    __syncthreads();

    int r16 = lane & 15;
    int kg  = lane >> 4;
    float aob0 = aob[0];
    unsigned short* h1w = s_h1 + wv * 16 * 64;

    // scores: per-wave private M-tiles, no barriers inside
    for (int m = wv; m < NMT; m += 4) {
        int row0 = m * 16;
        short8 a0 = ld8sw(s_hist, row0 + r16, kg * 8);
        short8 a1 = ld8sw(s_hist, row0 + r16, 32 + kg * 8);
        f32x4 d[4];
        #pragma unroll
        for (int n = 0; n < 4; ++n) {
            short8 b0 = ld8sw(s_WeffT, n * 16 + r16, kg * 8);
            short8 b1 = ld8sw(s_WeffT, n * 16 + r16, 32 + kg * 8);
            float qcv = s_qc[n * 16 + r16];
            f32x4 z = { qcv, qcv, qcv, qcv };          // C-init = qc[col] (col = lane&15)
            z = __builtin_amdgcn_mfma_f32_16x16x32_bf16(a0, b0, z, 0, 0, 0);
            z = __builtin_amdgcn_mfma_f32_16x16x32_bf16(a1, b1, z, 0, 0, 0);
            d[n] = z;
        }
        // h1 = relu(.)  D layout: col=lane&15, row=(lane>>4)*4+r  -> per-wave scratch
        #pragma unroll
        for (int n = 0; n < 4; ++n) {
            int col = n * 16 + r16;
            #pragma unroll
            for (int r = 0; r < 4; ++r)
                st16sw(h1w, kg * 4 + r, col, f2b(fmaxf(d[n][r], 0.f)));
        }
        // layer2 (wave-synchronous LDS reuse)
        short8 ha0 = ld8sw(h1w, r16, kg * 8);
        short8 ha1 = ld8sw(h1w, r16, 32 + kg * 8);
        f32x4 e[2];
        #pragma unroll
        for (int n = 0; n < 2; ++n) {
            short8 b0 = ld8sw(s_aw2T, n * 16 + r16, kg * 8);
            short8 b1 = ld8sw(s_aw2T, n * 16 + r16, 32 + kg * 8);
            f32x4 z = { 0.f, 0.f, 0.f, 0.f };
            z = __builtin_amdgcn_mfma_f32_16x16x32_bf16(ha0, b0, z, 0, 0, 0);
            z = __builtin_amdgcn_mfma_f32_16x16x32_bf16(ha1, b1, z, 0, 0, 0);
            e[n] = z;
        }
        // layer3: score = relu(h2 + ab2) @ aow (+aob), reduce across 16 lanes
        #pragma unroll
        for (int r = 0; r < 4; ++r) {
            float h20 = fmaxf(e[0][r] + s_ab2[r16], 0.f);
            float h21 = fmaxf(e[1][r] + s_ab2[16 + r16], 0.f);
            float p = h20 * s_aow[r16] + h21 * s_aow[16 + r16];
            p += __shfl_xor(p, 1);
            p += __shfl_xor(p, 2);
            p += __shfl_xor(p, 4);
            p += __shfl_xor(p, 8);
            if (r16 == 0) s_sc[row0 + kg * 4 + r] = p + aob0;
        }
    }
    __syncthreads();

    // softmax over t<200 (masked) — mask is int32
    float sc = -1e30f;
    if (tid < Tq) {
        int mk = mask[(long)b * Tq + tid];
        sc = mk ? s_sc[tid] : -1e9f;
    }
    float mx = sc;
    #pragma unroll
    for (int off = 1; off < 64; off <<= 1) mx = fmaxf(mx, __shfl_xor(mx, off));
    if (lane == 0) s_red[wv] = mx;
    __syncthreads();
    mx = fmaxf(fmaxf(s_red[0], s_red[1]), fmaxf(s_red[2], s_red[3]));
    float ex = (tid < Tq) ? expf(sc - mx) : 0.f;
    float sm = ex;
    #pragma unroll
    for (int off = 1; off < 64; off <<= 1) sm += __shfl_xor(sm, off);
    if (lane == 0) s_red[4 + wv] = sm;
    __syncthreads();
    float tot = s_red[4] + s_red[5] + s_red[6] + s_red[7];
    if (tid < Tq) s_sc[tid] = ex / tot;
    __syncthreads();

    // interest[j] = sum_t w_t * hist[t][j]  — straight from LDS (conflict-free)
    float acc = 0.f;
    for (int t = wv; t < Tq; t += 4)
        acc += s_sc[t] * b2f(ld16sw(s_hist, t, lane));
    s_intp[wv][lane] = acc;
    __syncthreads();
    if (tid < 64) {
        float inter = s_intp[0][tid] + s_intp[1][tid] + s_intp[2][tid] + s_intp[3][tid];
        mlpin[(long)b * 128 + tid] = s_q[tid];
        mlpin[(long)b * 128 + 64 + tid] = inter;
    }
}

// ---------------- KB: final MLP 128->256->128->1, fp32 ----------------
extern "C" __global__ __launch_bounds__(256) void k_final(
    const float* __restrict__ mlpin, const float* __restrict__ mw1,
    const float* __restrict__ mb1, const float* __restrict__ mw2,
    const float* __restrict__ mb2, const float* __restrict__ ow,
    const float* __restrict__ ob, float* __restrict__ out)
{
    __shared__ alignas(16) float s_in[16][128];
    __shared__ alignas(16) float s_g1[16][256];
    __shared__ alignas(16) float s_g2[16][128];
    int tid = threadIdx.x;
    long b0 = (long)blockIdx.x * 16;
    for (int idx = tid; idx < 2048; idx += 256) s_in[idx >> 7][idx & 127] = mlpin[b0 * 128 + idx];
    __syncthreads();
    {
        float acc[16];
        float bias = mb1[tid];
        #pragma unroll
        for (int r = 0; r < 16; ++r) acc[r] = bias;
        for (int i0 = 0; i0 < 128; i0 += 4) {
            float w0 = mw1[(i0 + 0) * 256 + tid];
            float w1 = mw1[(i0 + 1) * 256 + tid];
            float w2 = mw1[(i0 + 2) * 256 + tid];
            float w3 = mw1[(i0 + 3) * 256 + tid];
            #pragma unroll
            for (int r = 0; r < 16; ++r) {
                f32x4 e = *(const f32x4*)&s_in[r][i0];
                acc[r] += e.x * w0 + e.y * w1 + e.z * w2 + e.w * w3;
            }
        }
        #pragma unroll
        for (int r = 0; r < 16; ++r) s_g1[r][tid] = fmaxf(acc[r], 0.f);
    }
    __syncthreads();
    {
        int o = tid & 127, rh = tid >> 7;
        float acc[8];
        float bias = mb2[o];
        #pragma unroll
        for (int r = 0; r < 8; ++r) acc[r] = bias;
        for (int i0 = 0; i0 < 256; i0 += 4) {
            float w0 = mw2[(i0 + 0) * 128 + o];
            float w1 = mw2[(i0 + 1) * 128 + o];
            float w2 = mw2[(i0 + 2) * 128 + o];
            float w3 = mw2[(i0 + 3) * 128 + o];
            #pragma unroll
            for (int r = 0; r < 8; ++r) {
                f32x4 e = *(const f32x4*)&s_g1[rh * 8 + r][i0];
                acc[r] += e.x * w0 + e.y * w1 + e.z * w2 + e.w * w3;
            }
        }
        #pragma unroll
        for (int r = 0; r < 8; ++r) s_g2[rh * 8 + r][o] = fmaxf(acc[r], 0.f);
    }
    __syncthreads();
    {
        int r = tid >> 4, l16 = tid & 15;
        float acc = 0.f;
        for (int o = l16; o < 128; o += 16) acc += s_g2[r][o] * ow[o];
        acc += __shfl_xor(acc, 1);
        acc += __shfl_xor(acc, 2);
        acc += __shfl_xor(acc, 4);
        acc += __shfl_xor(acc, 8);
        if (l16 == 0) out[b0 + r] = acc + ob[0];
    }
}

extern "C" void kernel_launch(void* const* d_in, const int* in_sizes, int n_in,
                              void* d_out, int out_size, void* d_ws, size_t ws_size,
                              hipStream_t stream)
{
    const int*   target = (const int*)d_in[0];
    const int*   hist   = (const int*)d_in[1];
    const int*   mask   = (const int*)d_in[2];
    const float* embed  = (const float*)d_in[3];
    const float* aw1    = (const float*)d_in[4];
    const float* ab1    = (const float*)d_in[5];
    const float* aw2    = (const float*)d_in[6];
    const float* ab2    = (const float*)d_in[7];
    const float* aow    = (const float*)d_in[8];
    const float* aob    = (const float*)d_in[9];
    const float* mw1    = (const float*)d_in[10];
    const float* mb1    = (const float*)d_in[11];
    const float* mw2    = (const float*)d_in[12];
    const float* mb2    = (const float*)d_in[13];
    const float* ow     = (const float*)d_in[14];
    const float* ob     = (const float*)d_in[15];
    float* out = (float*)d_out;

    float* mlpin = (float*)d_ws;    // 4096*128*4 = 2 MB

    k_attn<<<Bq, 256, 0, stream>>>(target, hist, mask, embed, aw1, ab1, aw2,
                                   ab2, aow, aob, mlpin);
    k_final<<<Bq / 16, 256, 0, stream>>>(mlpin, mw1, mb1, mw2, mb2, ow, ob, out);
}

// Round 6
// 117.826 us; speedup vs baseline: 2.8573x; 1.1554x over previous
//
#include <hip/hip_runtime.h>
#include <stdint.h>

#define Bq 4096
#define Tq 200
#define TP 208      // padded to 13 tiles of 16
#define NMT 13
#define Vq 100000
#define BPB 8       // b's per k_weff block

typedef __attribute__((ext_vector_type(8))) short short8;   // 8 bf16 in 4 VGPRs
typedef __attribute__((ext_vector_type(4))) float f32x4;
typedef __attribute__((ext_vector_type(4))) unsigned short bfx4;
typedef __attribute__((ext_vector_type(4))) unsigned int u32x4;

static __device__ __forceinline__ unsigned short f2b(float f) {
    unsigned int u = __builtin_bit_cast(unsigned int, f);
    u = u + 0x7fffu + ((u >> 16) & 1u);            // RNE
    return (unsigned short)(u >> 16);
}
static __device__ __forceinline__ float b2f(unsigned short s) {
    unsigned int u = ((unsigned int)s) << 16;
    return __builtin_bit_cast(float, u);
}
// 2x f32 -> packed bf16 (RNE), single HW instr
static __device__ __forceinline__ unsigned int pack2(float lo, float hi) {
    unsigned int r;
    asm volatile("v_cvt_pk_bf16_f32 %0, %1, %2" : "=v"(r) : "v"(lo), "v"(hi));
    return r;
}

// swizzled [R][64]-bf16 tile helpers: byte = (row*128 + col*2) ^ ((row&7)<<4)
static __device__ __forceinline__ short8 ld8sw(const unsigned short* base, int row, int col8) {
    return *(const short8*)((const char*)base + (((row << 7) + (col8 << 1)) ^ ((row & 7) << 4)));
}
static __device__ __forceinline__ void st16sw(unsigned short* base, int row, int col, unsigned short v) {
    *(unsigned short*)((char*)base + (((row << 7) + (col << 1)) ^ ((row & 7) << 4))) = v;
}
static __device__ __forceinline__ void st64sw(unsigned short* base, int row, int col4, bfx4 v) {
    *(bfx4*)((char*)base + (((row << 7) + (col4 << 3)) ^ ((row & 7) << 4))) = v;
}
static __device__ __forceinline__ unsigned short ld16sw(const unsigned short* base, int row, int col) {
    return *(const unsigned short*)((const char*)base + (((row << 7) + (col << 1)) ^ ((row & 7) << 4)));
}

// ---------------- K0: per-b effective weights ----------------
// weff_all[b][j][i] = (W0+W2)[i][j] + q_b[i]*W3[i][j]   (bf16, j-major)
// qc_all[b][j]     = ab1[j] + sum_i q_b[i]*(W1-W2)[i][j]
// aw2t[k][j]       = aw2[j][k] (bf16)
extern "C" __global__ __launch_bounds__(256) void k_weff(
    const int* __restrict__ target, const float* __restrict__ embed,
    const float* __restrict__ aw1, const float* __restrict__ ab1,
    const float* __restrict__ aw2,
    unsigned short* __restrict__ weff_all, float* __restrict__ qc_all,
    unsigned short* __restrict__ aw2t)
{
    __shared__ float s_C[64][64];    // [i][j]
    __shared__ float s_W3[64][64];   // [i][j]
    __shared__ float s_W12T[64][64]; // [j][i]
    __shared__ float s_qb[BPB][64];
    int tid = threadIdx.x;
    int b0 = blockIdx.x * BPB;

    for (int idx = tid; idx < 4096; idx += 256) {
        int i = idx >> 6, j = idx & 63;
        float a0 = aw1[i * 64 + j];
        float a1 = aw1[(64 + i) * 64 + j];
        float a2 = aw1[(128 + i) * 64 + j];
        float a3 = aw1[(192 + i) * 64 + j];
        s_C[i][j] = a0 + a2;
        s_W3[i][j] = a3;
        s_W12T[j][i] = a1 - a2;
    }
    for (int idx = tid; idx < BPB * 64; idx += 256) {
        int bb = idx >> 6, j = idx & 63;
        s_qb[bb][j] = embed[(long)target[b0 + bb] * 64 + j];
    }
    if (blockIdx.x == 0) {
        for (int idx = tid; idx < 2048; idx += 256) {
            int j = idx >> 5, k = idx & 31;
            aw2t[k * 64 + j] = f2b(aw2[j * 32 + k]);
        }
    }
    __syncthreads();

    // qc
    for (int p = tid; p < BPB * 64; p += 256) {
        int bb = p >> 6, j = p & 63;
        float acc = ab1[j];
        #pragma unroll
        for (int i4 = 0; i4 < 64; i4 += 4) {
            f32x4 qv = *(const f32x4*)&s_qb[bb][i4];
            f32x4 wv = *(const f32x4*)&s_W12T[j][i4];
            acc += qv.x * wv.x + qv.y * wv.y + qv.z * wv.z + qv.w * wv.w;
        }
        qc_all[(long)(b0 + bb) * 64 + j] = acc;
    }
    // weff: thread owns (j = tid>>2, i0 = (tid&3)*16)
    int jw = tid >> 2, i0 = (tid & 3) << 4;
    for (int bb = 0; bb < BPB; ++bb) {
        unsigned int pk[8];
        #pragma unroll
        for (int u = 0; u < 8; ++u) {
            int i = i0 + u * 2;
            float w0 = s_C[i][jw] + s_qb[bb][i] * s_W3[i][jw];
            float w1 = s_C[i + 1][jw] + s_qb[bb][i + 1] * s_W3[i + 1][jw];
            pk[u] = pack2(w0, w1);
        }
        u32x4* dst = (u32x4*)(weff_all + (((long)(b0 + bb)) << 12) + jw * 64 + i0);
        u32x4 v0 = { pk[0], pk[1], pk[2], pk[3] };
        u32x4 v1 = { pk[4], pk[5], pk[6], pk[7] };
        dst[0] = v0;
        dst[1] = v1;
    }
}

// ---------------- KA fast: fused attention -> interest[b][64] ----------------
extern "C" __global__ __launch_bounds__(256, 4) void k_attn_fast(
    const int* __restrict__ hist, const int* __restrict__ mask,
    const float* __restrict__ embed,
    const float* __restrict__ ab2, const float* __restrict__ aow,
    const float* __restrict__ aob,
    const unsigned short* __restrict__ weff_all,
    const float* __restrict__ qc_all,
    const unsigned short* __restrict__ aw2t,
    float* __restrict__ inter64)
{
    __shared__ int s_id[TP];
    __shared__ alignas(16) unsigned short s_hist[TP * 64];    // bf16, swizzled
    __shared__ alignas(16) unsigned short s_h1[4 * 16 * 64];  // per-wave scratch, swizzled
    __shared__ float s_sc[TP];
    __shared__ float s_red[8];
    __shared__ float s_intp[4][64];

    int tid = threadIdx.x;
    int lane = tid & 63;
    int wv = tid >> 6;
    int b = blockIdx.x;
    int r16 = lane & 15;
    int kg = lane >> 4;

    // issue all B-fragment / constant loads up front (no LDS dependency -> latency hidden)
    short8 wf[4][2];
    #pragma unroll
    for (int n = 0; n < 4; ++n)
        #pragma unroll
        for (int h = 0; h < 2; ++h)
            wf[n][h] = *(const short8*)(weff_all + (((long)b) << 12) + (n * 16 + r16) * 64 + h * 32 + kg * 8);
    short8 af[2][2];
    #pragma unroll
    for (int n = 0; n < 2; ++n)
        #pragma unroll
        for (int h = 0; h < 2; ++h)
            af[n][h] = *(const short8*)(aw2t + (n * 16 + r16) * 64 + h * 32 + kg * 8);
    f32x4 qcz[4];
    #pragma unroll
    for (int n = 0; n < 4; ++n) {
        float v = qc_all[(long)b * 64 + n * 16 + r16];
        qcz[n].x = v; qcz[n].y = v; qcz[n].z = v; qcz[n].w = v;
    }
    float ab2a = ab2[r16], ab2b = ab2[16 + r16];
    float aowa = aow[r16], aowb = aow[16 + r16];
    float aob0 = aob[0];

    for (int t = tid; t < TP; t += 256) s_id[t] = hist[b * Tq + ((t < Tq) ? t : 0)];
    __syncthreads();

    // stage hist rows as bf16 (32B loads, packed 16B swizzled stores)
    for (int u = tid; u < TP * 8; u += 256) {
        int t = u >> 3, j8 = u & 7;
        const float* src = &embed[(long)s_id[t] * 64 + j8 * 8];
        f32x4 e0 = *(const f32x4*)src;
        f32x4 e1 = *(const f32x4*)(src + 4);
        u32x4 pk = { pack2(e0.x, e0.y), pack2(e0.z, e0.w),
                     pack2(e1.x, e1.y), pack2(e1.z, e1.w) };
        *(u32x4*)((char*)s_hist + (((t << 7) + (j8 << 4)) ^ ((t & 7) << 4))) = pk;
    }
    __syncthreads();

    unsigned short* h1w = s_h1 + wv * 16 * 64;

    // scores: per-wave private M-tiles, no barriers inside
    for (int m = wv; m < NMT; m += 4) {
        int row0 = m * 16;
        short8 a0 = ld8sw(s_hist, row0 + r16, kg * 8);
        short8 a1 = ld8sw(s_hist, row0 + r16, 32 + kg * 8);
        f32x4 d[4];
        #pragma unroll
        for (int n = 0; n < 4; ++n) {
            f32x4 z = qcz[n];
            z = __builtin_amdgcn_mfma_f32_16x16x32_bf16(a0, wf[n][0], z, 0, 0, 0);
            z = __builtin_amdgcn_mfma_f32_16x16x32_bf16(a1, wf[n][1], z, 0, 0, 0);
            d[n] = z;
        }
        // h1 = relu(.)  D layout: col=lane&15, row=(lane>>4)*4+r
        #pragma unroll
        for (int n = 0; n < 4; ++n) {
            int col = n * 16 + r16;
            #pragma unroll
            for (int r = 0; r < 4; ++r)
                st16sw(h1w, kg * 4 + r, col, f2b(fmaxf(d[n][r], 0.f)));
        }
        short8 ha0 = ld8sw(h1w, r16, kg * 8);
        short8 ha1 = ld8sw(h1w, r16, 32 + kg * 8);
        f32x4 e[2];
        #pragma unroll
        for (int n = 0; n < 2; ++n) {
            f32x4 z = { 0.f, 0.f, 0.f, 0.f };
            z = __builtin_amdgcn_mfma_f32_16x16x32_bf16(ha0, af[n][0], z, 0, 0, 0);
            z = __builtin_amdgcn_mfma_f32_16x16x32_bf16(ha1, af[n][1], z, 0, 0, 0);
            e[n] = z;
        }
        #pragma unroll
        for (int r = 0; r < 4; ++r) {
            float h20 = fmaxf(e[0][r] + ab2a, 0.f);
            float h21 = fmaxf(e[1][r] + ab2b, 0.f);
            float p = h20 * aowa + h21 * aowb;
            p += __shfl_xor(p, 1);
            p += __shfl_xor(p, 2);
            p += __shfl_xor(p, 4);
            p += __shfl_xor(p, 8);
            if (r16 == 0) s_sc[row0 + kg * 4 + r] = p + aob0;
        }
    }
    __syncthreads();

    // softmax over t<200 (masked; mask is int32)
    float sc = -1e30f;
    if (tid < Tq) {
        int mk = mask[(long)b * Tq + tid];
        sc = mk ? s_sc[tid] : -1e9f;
    }
    float mx = sc;
    #pragma unroll
    for (int off = 1; off < 64; off <<= 1) mx = fmaxf(mx, __shfl_xor(mx, off));
    if (lane == 0) s_red[wv] = mx;
    __syncthreads();
    mx = fmaxf(fmaxf(s_red[0], s_red[1]), fmaxf(s_red[2], s_red[3]));
    float ex = (tid < Tq) ? expf(sc - mx) : 0.f;
    float sm = ex;
    #pragma unroll
    for (int off = 1; off < 64; off <<= 1) sm += __shfl_xor(sm, off);
    if (lane == 0) s_red[4 + wv] = sm;
    __syncthreads();
    float tot = s_red[4] + s_red[5] + s_red[6] + s_red[7];
    if (tid < Tq) s_sc[tid] = ex / tot;
    else if (tid < TP) s_sc[tid] = 0.f;
    __syncthreads();

    // interest: 8 rows x 8 col-groups per wave-op, wide conflict-free LDS reads
    int cg = lane & 7;   // cols cg*8..+7
    int tg = lane >> 3;  // row within 8-row group
    float acc8[8];
    #pragma unroll
    for (int u = 0; u < 8; ++u) acc8[u] = 0.f;
    for (int t = wv * 8 + tg; t < TP; t += 32) {
        float w = s_sc[t];
        short8 h = ld8sw(s_hist, t, cg * 8);
        #pragma unroll
        for (int u = 0; u < 8; ++u) acc8[u] += w * b2f((unsigned short)h[u]);
    }
    #pragma unroll
    for (int u = 0; u < 8; ++u) {
        acc8[u] += __shfl_xor(acc8[u], 8);
        acc8[u] += __shfl_xor(acc8[u], 16);
        acc8[u] += __shfl_xor(acc8[u], 32);
    }
    if (tg == 0) {
        #pragma unroll
        for (int u = 0; u < 8; ++u) s_intp[wv][cg * 8 + u] = acc8[u];
    }
    __syncthreads();
    if (tid < 64)
        inter64[(long)b * 64 + tid] = s_intp[0][tid] + s_intp[1][tid] + s_intp[2][tid] + s_intp[3][tid];
}

// ---------------- KA fallback (round-5 proven path, used if ws too small) ----------------
extern "C" __global__ __launch_bounds__(256, 3) void k_attn_fb(
    const int* __restrict__ target, const int* __restrict__ hist,
    const int* __restrict__ mask,
    const float* __restrict__ embed, const float* __restrict__ aw1,
    const float* __restrict__ ab1, const float* __restrict__ aw2,
    const float* __restrict__ ab2, const float* __restrict__ aow,
    const float* __restrict__ aob,
    float* __restrict__ inter64)
{
    __shared__ int s_id[TP];
    __shared__ float s_q[64];
    __shared__ float s_qc[64];
    __shared__ float s_qcp[4][64];
    __shared__ alignas(16) unsigned short s_hist[TP * 64];
    __shared__ alignas(16) unsigned short s_WeffT[64 * 64];
    __shared__ alignas(16) unsigned short s_aw2T[32 * 64];
    __shared__ alignas(16) unsigned short s_h1[4 * 16 * 64];
    __shared__ float s_sc[TP];
    __shared__ float s_aow[32];
    __shared__ float s_ab2[32];
    __shared__ float s_red[8];
    __shared__ float s_intp[4][64];

    int tid = threadIdx.x;
    int lane = tid & 63;
    int wv = tid >> 6;
    int b = blockIdx.x;

    int tgt = target[b];
    if (tid < 64) s_q[tid] = embed[(long)tgt * 64 + tid];
    for (int t = tid; t < TP; t += 256) s_id[t] = hist[b * Tq + ((t < Tq) ? t : 0)];
    if (tid < 32) { s_aow[tid] = aow[tid]; s_ab2[tid] = ab2[tid]; }
    __syncthreads();

    for (int idx = tid; idx < 4096; idx += 256) {
        int i = idx >> 6, j = idx & 63;
        float w = aw1[i * 64 + j] + aw1[(128 + i) * 64 + j] + s_q[i] * aw1[(192 + i) * 64 + j];
        st16sw(s_WeffT, j, i, f2b(w));
    }
    for (int idx = tid; idx < 2048; idx += 256) {
        int j = idx >> 5, k = idx & 31;
        st16sw(s_aw2T, k, j, f2b(aw2[j * 32 + k]));
    }
    {
        float acc = 0.f;
        #pragma unroll
        for (int ii = 0; ii < 16; ++ii) {
            int i = wv * 16 + ii;
            acc += s_q[i] * (aw1[(64 + i) * 64 + lane] - aw1[(128 + i) * 64 + lane]);
        }
        s_qcp[wv][lane] = acc;
    }
    for (int u = tid; u < TP * 16; u += 256) {
        int t = u >> 4, j4 = u & 15;
        f32x4 e = *(const f32x4*)&embed[(long)s_id[t] * 64 + j4 * 4];
        bfx4 p = { f2b(e.x), f2b(e.y), f2b(e.z), f2b(e.w) };
        st64sw(s_hist, t, j4, p);
    }
    __syncthreads();
    if (tid < 64) s_qc[tid] = ab1[tid] + s_qcp[0][tid] + s_qcp[1][tid] + s_qcp[2][tid] + s_qcp[3][tid];
    __syncthreads();

    int r16 = lane & 15;
    int kg = lane >> 4;
    float aob0 = aob[0];
    unsigned short* h1w = s_h1 + wv * 16 * 64;

    for (int m = wv; m < NMT; m += 4) {
        int row0 = m * 16;
        short8 a0 = ld8sw(s_hist, row0 + r16, kg * 8);
        short8 a1 = ld8sw(s_hist, row0 + r16, 32 + kg * 8);
        f32x4 d[4];
        #pragma unroll
        for (int n = 0; n < 4; ++n) {
            short8 b0 = ld8sw(s_WeffT, n * 16 + r16, kg * 8);
            short8 b1 = ld8sw(s_WeffT, n * 16 + r16, 32 + kg * 8);
            float qcv = s_qc[n * 16 + r16];
            f32x4 z = { qcv, qcv, qcv, qcv };
            z = __builtin_amdgcn_mfma_f32_16x16x32_bf16(a0, b0, z, 0, 0, 0);
            z = __builtin_amdgcn_mfma_f32_16x16x32_bf16(a1, b1, z, 0, 0, 0);
            d[n] = z;
        }
        #pragma unroll
        for (int n = 0; n < 4; ++n) {
            int col = n * 16 + r16;
            #pragma unroll
            for (int r = 0; r < 4; ++r)
                st16sw(h1w, kg * 4 + r, col, f2b(fmaxf(d[n][r], 0.f)));
        }
        short8 ha0 = ld8sw(h1w, r16, kg * 8);
        short8 ha1 = ld8sw(h1w, r16, 32 + kg * 8);
        f32x4 e[2];
        #pragma unroll
        for (int n = 0; n < 2; ++n) {
            short8 b0 = ld8sw(s_aw2T, n * 16 + r16, kg * 8);
            short8 b1 = ld8sw(s_aw2T, n * 16 + r16, 32 + kg * 8);
            f32x4 z = { 0.f, 0.f, 0.f, 0.f };
            z = __builtin_amdgcn_mfma_f32_16x16x32_bf16(ha0, b0, z, 0, 0, 0);
            z = __builtin_amdgcn_mfma_f32_16x16x32_bf16(ha1, b1, z, 0, 0, 0);
            e[n] = z;
        }
        #pragma unroll
        for (int r = 0; r < 4; ++r) {
            float h20 = fmaxf(e[0][r] + s_ab2[r16], 0.f);
            float h21 = fmaxf(e[1][r] + s_ab2[16 + r16], 0.f);
            float p = h20 * s_aow[r16] + h21 * s_aow[16 + r16];
            p += __shfl_xor(p, 1);
            p += __shfl_xor(p, 2);
            p += __shfl_xor(p, 4);
            p += __shfl_xor(p, 8);
            if (r16 == 0) s_sc[row0 + kg * 4 + r] = p + aob0;
        }
    }
    __syncthreads();

    float sc = -1e30f;
    if (tid < Tq) {
        int mk = mask[(long)b * Tq + tid];
        sc = mk ? s_sc[tid] : -1e9f;
    }
    float mx = sc;
    #pragma unroll
    for (int off = 1; off < 64; off <<= 1) mx = fmaxf(mx, __shfl_xor(mx, off));
    if (lane == 0) s_red[wv] = mx;
    __syncthreads();
    mx = fmaxf(fmaxf(s_red[0], s_red[1]), fmaxf(s_red[2], s_red[3]));
    float ex = (tid < Tq) ? expf(sc - mx) : 0.f;
    float sm = ex;
    #pragma unroll
    for (int off = 1; off < 64; off <<= 1) sm += __shfl_xor(sm, off);
    if (lane == 0) s_red[4 + wv] = sm;
    __syncthreads();
    float tot = s_red[4] + s_red[5] + s_red[6] + s_red[7];
    if (tid < Tq) s_sc[tid] = ex / tot;
    __syncthreads();

    float acc = 0.f;
    for (int t = wv; t < Tq; t += 4)
        acc += s_sc[t] * b2f(ld16sw(s_hist, t, lane));
    s_intp[wv][lane] = acc;
    __syncthreads();
    if (tid < 64)
        inter64[(long)b * 64 + tid] = s_intp[0][tid] + s_intp[1][tid] + s_intp[2][tid] + s_intp[3][tid];
}

// ---------------- KB: final MLP [q | interest] 128->256->128->1, fp32 ----------------
extern "C" __global__ __launch_bounds__(256) void k_final(
    const int* __restrict__ target, const float* __restrict__ embed,
    const float* __restrict__ inter64, const float* __restrict__ mw1,
    const float* __restrict__ mb1, const float* __restrict__ mw2,
    const float* __restrict__ mb2, const float* __restrict__ ow,
    const float* __restrict__ ob, float* __restrict__ out)
{
    __shared__ alignas(16) float s_in[16][128];
    __shared__ alignas(16) float s_g1[16][256];
    __shared__ alignas(16) float s_g2[16][128];
    int tid = threadIdx.x;
    long b0 = (long)blockIdx.x * 16;
    for (int idx = tid; idx < 1024; idx += 256) {
        int r = idx >> 6, j = idx & 63;
        s_in[r][j] = embed[(long)target[b0 + r] * 64 + j];
        s_in[r][64 + j] = inter64[b0 * 64 + idx];
    }
    __syncthreads();
    {
        float acc[16];
        float bias = mb1[tid];
        #pragma unroll
        for (int r = 0; r < 16; ++r) acc[r] = bias;
        for (int i0 = 0; i0 < 128; i0 += 4) {
            float w0 = mw1[(i0 + 0) * 256 + tid];
            float w1 = mw1[(i0 + 1) * 256 + tid];
            float w2 = mw1[(i0 + 2) * 256 + tid];
            float w3 = mw1[(i0 + 3) * 256 + tid];
            #pragma unroll
            for (int r = 0; r < 16; ++r) {
                f32x4 e = *(const f32x4*)&s_in[r][i0];
                acc[r] += e.x * w0 + e.y * w1 + e.z * w2 + e.w * w3;
            }
        }
        #pragma unroll
        for (int r = 0; r < 16; ++r) s_g1[r][tid] = fmaxf(acc[r], 0.f);
    }
    __syncthreads();
    {
        int o = tid & 127, rh = tid >> 7;
        float acc[8];
        float bias = mb2[o];
        #pragma unroll
        for (int r = 0; r < 8; ++r) acc[r] = bias;
        for (int i0 = 0; i0 < 256; i0 += 4) {
            float w0 = mw2[(i0 + 0) * 128 + o];
            float w1 = mw2[(i0 + 1) * 128 + o];
            float w2 = mw2[(i0 + 2) * 128 + o];
            float w3 = mw2[(i0 + 3) * 128 + o];
            #pragma unroll
            for (int r = 0; r < 8; ++r) {
                f32x4 e = *(const f32x4*)&s_g1[rh * 8 + r][i0];
                acc[r] += e.x * w0 + e.y * w1 + e.z * w2 + e.w * w3;
            }
        }
        #pragma unroll
        for (int r = 0; r < 8; ++r) s_g2[rh * 8 + r][o] = fmaxf(acc[r], 0.f);
    }
    __syncthreads();
    {
        int r = tid >> 4, l16 = tid & 15;
        float acc = 0.f;
        for (int o = l16; o < 128; o += 16) acc += s_g2[r][o] * ow[o];
        acc += __shfl_xor(acc, 1);
        acc += __shfl_xor(acc, 2);
        acc += __shfl_xor(acc, 4);
        acc += __shfl_xor(acc, 8);
        if (l16 == 0) out[b0 + r] = acc + ob[0];
    }
}

extern "C" void kernel_launch(void* const* d_in, const int* in_sizes, int n_in,
                              void* d_out, int out_size, void* d_ws, size_t ws_size,
                              hipStream_t stream)
{
    const int*   target = (const int*)d_in[0];
    const int*   hist   = (const int*)d_in[1];
    const int*   mask   = (const int*)d_in[2];
    const float* embed  = (const float*)d_in[3];
    const float* aw1    = (const float*)d_in[4];
    const float* ab1    = (const float*)d_in[5];
    const float* aw2    = (const float*)d_in[6];
    const float* ab2    = (const float*)d_in[7];
    const float* aow    = (const float*)d_in[8];
    const float* aob    = (const float*)d_in[9];
    const float* mw1    = (const float*)d_in[10];
    const float* mb1    = (const float*)d_in[11];
    const float* mw2    = (const float*)d_in[12];
    const float* mb2    = (const float*)d_in[13];
    const float* ow     = (const float*)d_in[14];
    const float* ob     = (const float*)d_in[15];
    float* out = (float*)d_out;

    const size_t WEFF_B = (size_t)Bq * 4096 * 2;   // 32 MB
    const size_t QC_B   = (size_t)Bq * 64 * 4;     // 1 MB
    const size_t AW2T_B = 4096;                    // 4 KB
    const size_t INT_B  = (size_t)Bq * 64 * 4;     // 1 MB
    char* p = (char*)d_ws;

    if (ws_size >= WEFF_B + QC_B + AW2T_B + INT_B) {
        unsigned short* weff  = (unsigned short*)p;
        float*          qc    = (float*)(p + WEFF_B);
        unsigned short* aw2t  = (unsigned short*)(p + WEFF_B + QC_B);
        float*          inter = (float*)(p + WEFF_B + QC_B + AW2T_B);
        k_weff<<<Bq / BPB, 256, 0, stream>>>(target, embed, aw1, ab1, aw2, weff, qc, aw2t);
        k_attn_fast<<<Bq, 256, 0, stream>>>(hist, mask, embed, ab2, aow, aob,
                                            weff, qc, aw2t, inter);
        k_final<<<Bq / 16, 256, 0, stream>>>(target, embed, inter, mw1, mb1, mw2,
                                             mb2, ow, ob, out);
    } else {
        float* inter = (float*)p;                  // 1 MB
        k_attn_fb<<<Bq, 256, 0, stream>>>(target, hist, mask, embed, aw1, ab1,
                                          aw2, ab2, aow, aob, inter);
        k_final<<<Bq / 16, 256, 0, stream>>>(target, embed, inter, mw1, mb1, mw2,
                                             mb2, ow, ob, out);
    }
}